// Round 5
// baseline (185.561 us; speedup 1.0000x reference)
//
#include <hip/hip_runtime.h>
#include <hip/hip_fp16.h>
#include <hip/hip_bf16.h>

// Logic-gate network: 23 layers, widths [128]*16 + [64,32,16,8,4,2,1].
// Node j: out = c0 + c1*a + c2*b + c3*a*b; c = softmax(W[j]) @ GATE_COEFFS.
// N_CELLS = 262144 independent cells.
//
// R5: 4 cells per lane (2x half2 = uint2, ds_read_b64 at ~85 B/cy vs b32's
// ~44) -> LDS cycles per cell halved; 256 cells/block. Single 64KB buffer,
// 2 barriers/layer; __launch_bounds__(512,4) -> 128 VGPR cap so res[16]
// (32 VGPRs) stays in registers (R4's 64-cap spilled it -> 19MB HBM writes).
// fp16 storage / fp32 math (absmax 1.95e-3, thr 9.26e-3).

#define N_CELLS     262144
#define TOTAL_NODES 2175
#define CELLS       256        // cells per block (64 lanes x 4 packed fp16)
#define BLOCK       512        // 8 waves
#define ROWS        128        // max layer width

__device__ const float GC[16][4] = {
    {0, 0, 0, 0}, {0, 0, 0, 1}, {0, 1, 0, -1}, {0, 1, 0, 0},
    {0, 0, 1, -1}, {0, 0, 1, 0}, {0, 1, 1, -2}, {0, 1, 1, -1},
    {1, -1, -1, 1}, {1, -1, -1, 2}, {1, 0, -1, 0}, {1, 0, -1, 1},
    {1, -1, 0, 0}, {1, -1, 0, 1}, {1, 0, 0, -1}, {1, 0, 0, 0}
};

// 32B node descriptor: one wave-uniform scalar-load stream in the hot loop.
struct __align__(32) NodeDesc {
    float c0, c1, c2, c3;
    int   ia, ib;
    int   pad0, pad1;
};

// ---- Kernel A: build per-node descriptors: c = softmax(W[node]) @ GC ----
__global__ void coeff_kernel(const float* __restrict__ W,
                             const int* __restrict__ idx_a,
                             const int* __restrict__ idx_b,
                             NodeDesc* __restrict__ dout) {
    int node = blockIdx.x * blockDim.x + threadIdx.x;
    if (node >= TOTAL_NODES) return;
    const float* w = W + node * 16;
    float v[16];
    float m = -1e30f;
    #pragma unroll
    for (int i = 0; i < 16; ++i) { v[i] = w[i]; m = fmaxf(m, v[i]); }
    float s = 0.f;
    #pragma unroll
    for (int i = 0; i < 16; ++i) { v[i] = expf(v[i] - m); s += v[i]; }
    float inv = 1.0f / s;
    float c0 = 0.f, c1 = 0.f, c2 = 0.f, c3 = 0.f;
    #pragma unroll
    for (int i = 0; i < 16; ++i) {
        float p = v[i] * inv;
        c0 += p * GC[i][0];
        c1 += p * GC[i][1];
        c2 += p * GC[i][2];
        c3 += p * GC[i][3];
    }
    NodeDesc d;
    d.c0 = c0; d.c1 = c1; d.c2 = c2; d.c3 = c3;
    d.ia = idx_a[node]; d.ib = idx_b[node];
    d.pad0 = 0; d.pad1 = 0;
    dout[node] = d;
}

__device__ __forceinline__ float2 h2f(unsigned int u) {
    __half2 h = *reinterpret_cast<__half2*>(&u);
    return __half22float2(h);
}
__device__ __forceinline__ unsigned int f2h(float lo, float hi) {
    __half2 h = __floats2half2_rn(lo, hi);
    return *reinterpret_cast<unsigned int*>(&h);
}

// One layer: wave q computes nodes [q*PER, q*PER+PER).
// Phase 1: gather + compute into res[] (regs). Barrier.
// Phase 2: write res[] over the (now dead) input rows. Barrier.
template<int PER>
__device__ __forceinline__ void layer_step(const NodeDesc* __restrict__ desc,
                                           int off, int w,
                                           uint2 (* __restrict__ buf)[64],
                                           int q, int lane) {
    const int n0 = q * PER;
    uint2 res[PER];
    const bool active = (n0 < w);

    if (active) {
        #pragma unroll
        for (int j = 0; j < PER; ++j) {
            int nu = __builtin_amdgcn_readfirstlane(n0 + j);
            NodeDesc d = desc[off + nu];          // scalar loads
            uint2 ap = buf[d.ia][lane];           // ds_read_b64
            uint2 bp = buf[d.ib][lane];
            float2 a01 = h2f(ap.x), a23 = h2f(ap.y);
            float2 b01 = h2f(bp.x), b23 = h2f(bp.y);
            // out = a*(c1 + c3*b) + (c0 + c2*b)   (3 FMA per cell, f32)
            float r0 = fmaf(a01.x, fmaf(d.c3, b01.x, d.c1), fmaf(d.c2, b01.x, d.c0));
            float r1 = fmaf(a01.y, fmaf(d.c3, b01.y, d.c1), fmaf(d.c2, b01.y, d.c0));
            float r2 = fmaf(a23.x, fmaf(d.c3, b23.x, d.c1), fmaf(d.c2, b23.x, d.c0));
            float r3 = fmaf(a23.y, fmaf(d.c3, b23.y, d.c1), fmaf(d.c2, b23.y, d.c0));
            res[j].x = f2h(r0, r1);
            res[j].y = f2h(r2, r3);
        }
    }
    __syncthreads();                              // all reads done
    if (active) {
        #pragma unroll
        for (int j = 0; j < PER; ++j) {
            int nu = __builtin_amdgcn_readfirstlane(n0 + j);
            buf[nu][lane] = res[j];               // ds_write_b64
        }
    }
    __syncthreads();                              // all writes done
}

// ---- Kernel B: the network. 256 cells/block; single 64KB LDS buffer. ----
__global__ __launch_bounds__(BLOCK, 4)
void net_kernel(const float* __restrict__ x,
                const NodeDesc* __restrict__ desc,
                float* __restrict__ out) {
    // 128 rows * 64 lanes * 8B = 64 KB -> 2 blocks/CU (16 waves/CU).
    __shared__ uint2 buf[ROWS][64];

    const int t    = threadIdx.x;
    const int lane = t & 63;        // cells lane, lane+64, lane+128, lane+192
    const int q    = t >> 6;        // wave id
    const size_t base = (size_t)blockIdx.x * CELLS;

    // Stage x (256 cells x 16 f32 = 16 KB) -> packed fp16 buf[k][lane][4].
    {
        const float4* xv = reinterpret_cast<const float4*>(x + base * 16);
        __half* hp = reinterpret_cast<__half*>(&buf[0][0]);
        #pragma unroll
        for (int r = 0; r < 2; ++r) {
            int i = t + r * BLOCK;            // float4 index 0..1023
            float4 v = xv[i];                 // coalesced
            int c  = i >> 2;                  // cell 0..255
            int k  = (i & 3) << 2;            // feature base
            int h  = c >> 6;                  // sub-slot 0..3
            int cl = c & 63;
            hp[((k + 0) * 64 + cl) * 4 + h] = __float2half(v.x);
            hp[((k + 1) * 64 + cl) * 4 + h] = __float2half(v.y);
            hp[((k + 2) * 64 + cl) * 4 + h] = __float2half(v.z);
            hp[((k + 3) * 64 + cl) * 4 + h] = __float2half(v.w);
        }
    }
    __syncthreads();

    // Layers 0..15: width 128, PER=16.
    #pragma unroll 1
    for (int li = 0; li < 16; ++li)
        layer_step<16>(desc, li * 128, 128, buf, q, lane);
    // Tail: widths 64,32,16,8,4,2,1.
    layer_step<8>(desc, 2048, 64, buf, q, lane);
    layer_step<4>(desc, 2112, 32, buf, q, lane);
    layer_step<2>(desc, 2144, 16, buf, q, lane);
    layer_step<1>(desc, 2160,  8, buf, q, lane);
    layer_step<1>(desc, 2168,  4, buf, q, lane);
    layer_step<1>(desc, 2172,  2, buf, q, lane);
    layer_step<1>(desc, 2174,  1, buf, q, lane);

    // Final layer width 1: row 0, 4 packed cells per lane.
    if (t < CELLS) {
        int cl = t & 63, h = t >> 6;
        uint2 p = buf[0][cl];                 // broadcast read
        unsigned int u = (h < 2) ? p.x : p.y;
        __half2 hh = *reinterpret_cast<__half2*>(&u);
        out[base + t] = (h & 1) ? __high2float(hh) : __low2float(hh);
    }
}

extern "C" void kernel_launch(void* const* d_in, const int* in_sizes, int n_in,
                              void* d_out, int out_size, void* d_ws, size_t ws_size,
                              hipStream_t stream) {
    const float* x  = (const float*)d_in[0];
    const float* W  = (const float*)d_in[1];
    const int*   ia = (const int*)d_in[2];
    const int*   ib = (const int*)d_in[3];
    NodeDesc* desc  = (NodeDesc*)d_ws;   // 2175 * 32 B = 69.6 KB scratch

    coeff_kernel<<<(TOTAL_NODES + 255) / 256, 256, 0, stream>>>(W, ia, ib, desc);

    const int grid = N_CELLS / CELLS;    // 1024 blocks
    net_kernel<<<grid, BLOCK, 0, stream>>>(x, desc, (float*)d_out);
}

// Round 7
// 175.113 us; speedup vs baseline: 1.0597x; 1.0597x over previous
//
#include <hip/hip_runtime.h>
#include <hip/hip_fp16.h>
#include <hip/hip_bf16.h>

// Logic-gate network: 23 layers, widths [128]*16 + [64,32,16,8,4,2,1].
// Node j: out = c0 + c1*a + c2*b + c3*a*b; c = softmax(W[j]) @ GATE_COEFFS.
// N_CELLS = 262144 independent cells.
//
// R6: R5's b64 data path (4 fp16 cells/lane) + max residency. 1024 threads
// (16 waves) x 64KB LDS -> 2 blocks/CU = 32 waves/CU (chip max), vs R5's 16.
// R5 lesson: VALU (~71us) and DS (~65us) floors were NOT overlapping at 16
// waves/CU (130us ~= sum). res[8] = 16 VGPR; __launch_bounds__(1024,8) caps
// VGPR at 64, est usage ~40 -> no spill (watch WRITE_SIZE as the tripwire).
// fp16 storage / fp32 math (absmax 1.95e-3, thr 9.26e-3).

#define N_CELLS     262144
#define TOTAL_NODES 2175
#define CELLS       256        // cells per block (64 lanes x 4 packed fp16)
#define BLOCK       1024       // 16 waves
#define ROWS        128        // max layer width

__device__ const float GC[16][4] = {
    {0, 0, 0, 0}, {0, 0, 0, 1}, {0, 1, 0, -1}, {0, 1, 0, 0},
    {0, 0, 1, -1}, {0, 0, 1, 0}, {0, 1, 1, -2}, {0, 1, 1, -1},
    {1, -1, -1, 1}, {1, -1, -1, 2}, {1, 0, -1, 0}, {1, 0, -1, 1},
    {1, -1, 0, 0}, {1, -1, 0, 1}, {1, 0, 0, -1}, {1, 0, 0, 0}
};

// 32B node descriptor: one wave-uniform scalar-load stream in the hot loop.
struct __align__(32) NodeDesc {
    float c0, c1, c2, c3;
    int   ia, ib;
    int   pad0, pad1;
};

// ---- Kernel A: build per-node descriptors: c = softmax(W[node]) @ GC ----
__global__ void coeff_kernel(const float* __restrict__ W,
                             const int* __restrict__ idx_a,
                             const int* __restrict__ idx_b,
                             NodeDesc* __restrict__ dout) {
    int node = blockIdx.x * blockDim.x + threadIdx.x;
    if (node >= TOTAL_NODES) return;
    const float* w = W + node * 16;
    float v[16];
    float m = -1e30f;
    #pragma unroll
    for (int i = 0; i < 16; ++i) { v[i] = w[i]; m = fmaxf(m, v[i]); }
    float s = 0.f;
    #pragma unroll
    for (int i = 0; i < 16; ++i) { v[i] = expf(v[i] - m); s += v[i]; }
    float inv = 1.0f / s;
    float c0 = 0.f, c1 = 0.f, c2 = 0.f, c3 = 0.f;
    #pragma unroll
    for (int i = 0; i < 16; ++i) {
        float p = v[i] * inv;
        c0 += p * GC[i][0];
        c1 += p * GC[i][1];
        c2 += p * GC[i][2];
        c3 += p * GC[i][3];
    }
    NodeDesc d;
    d.c0 = c0; d.c1 = c1; d.c2 = c2; d.c3 = c3;
    d.ia = idx_a[node]; d.ib = idx_b[node];
    d.pad0 = 0; d.pad1 = 0;
    dout[node] = d;
}

__device__ __forceinline__ float2 h2f(unsigned int u) {
    __half2 h = *reinterpret_cast<__half2*>(&u);
    return __half22float2(h);
}
__device__ __forceinline__ unsigned int f2h(float lo, float hi) {
    __half2 h = __floats2half2_rn(lo, hi);
    return *reinterpret_cast<unsigned int*>(&h);
}

// One layer: wave q computes nodes [q*PER, q*PER+PER).
// Phase 1: gather + compute into res[] (regs). Barrier.
// Phase 2: write res[] over the (now dead) input rows. Barrier.
template<int PER>
__device__ __forceinline__ void layer_step(const NodeDesc* __restrict__ desc,
                                           int off, int w,
                                           uint2 (* __restrict__ buf)[64],
                                           int q, int lane) {
    const int n0 = q * PER;
    uint2 res[PER];
    const bool active = (n0 < w);

    if (active) {
        #pragma unroll
        for (int j = 0; j < PER; ++j) {
            int nu = __builtin_amdgcn_readfirstlane(n0 + j);
            NodeDesc d = desc[off + nu];          // scalar loads
            uint2 ap = buf[d.ia][lane];           // ds_read_b64
            uint2 bp = buf[d.ib][lane];
            float2 a01 = h2f(ap.x), a23 = h2f(ap.y);
            float2 b01 = h2f(bp.x), b23 = h2f(bp.y);
            // out = a*(c1 + c3*b) + (c0 + c2*b)   (3 FMA per cell, f32)
            float r0 = fmaf(a01.x, fmaf(d.c3, b01.x, d.c1), fmaf(d.c2, b01.x, d.c0));
            float r1 = fmaf(a01.y, fmaf(d.c3, b01.y, d.c1), fmaf(d.c2, b01.y, d.c0));
            float r2 = fmaf(a23.x, fmaf(d.c3, b23.x, d.c1), fmaf(d.c2, b23.x, d.c0));
            float r3 = fmaf(a23.y, fmaf(d.c3, b23.y, d.c1), fmaf(d.c2, b23.y, d.c0));
            res[j].x = f2h(r0, r1);
            res[j].y = f2h(r2, r3);
        }
    }
    __syncthreads();                              // all reads done
    if (active) {
        #pragma unroll
        for (int j = 0; j < PER; ++j) {
            int nu = __builtin_amdgcn_readfirstlane(n0 + j);
            buf[nu][lane] = res[j];               // ds_write_b64
        }
    }
    __syncthreads();                              // all writes done
}

// ---- Kernel B: the network. 256 cells/block; single 64KB LDS buffer. ----
__global__ __launch_bounds__(BLOCK, 8)
void net_kernel(const float* __restrict__ x,
                const NodeDesc* __restrict__ desc,
                float* __restrict__ out) {
    // 128 rows * 64 lanes * 8B = 64 KB -> 2 blocks/CU (32 waves/CU, chip max).
    __shared__ uint2 buf[ROWS][64];

    const int t    = threadIdx.x;
    const int lane = t & 63;        // cells lane, lane+64, lane+128, lane+192
    const int q    = t >> 6;        // wave id 0..15
    const size_t base = (size_t)blockIdx.x * CELLS;

    // Stage x (256 cells x 16 f32 = 16 KB) -> packed fp16 buf[k][lane][4].
    {
        const float4* xv = reinterpret_cast<const float4*>(x + base * 16);
        __half* hp = reinterpret_cast<__half*>(&buf[0][0]);
        float4 v = xv[t];                 // coalesced: 1024 float4 = 4096 f32
        int c  = t >> 2;                  // cell 0..255
        int k  = (t & 3) << 2;            // feature base
        int h  = c >> 6;                  // sub-slot 0..3
        int cl = c & 63;
        hp[((k + 0) * 64 + cl) * 4 + h] = __float2half(v.x);
        hp[((k + 1) * 64 + cl) * 4 + h] = __float2half(v.y);
        hp[((k + 2) * 64 + cl) * 4 + h] = __float2half(v.z);
        hp[((k + 3) * 64 + cl) * 4 + h] = __float2half(v.w);
    }
    __syncthreads();

    // Layers 0..15: width 128, PER=8 (16 waves).
    #pragma unroll 1
    for (int li = 0; li < 16; ++li)
        layer_step<8>(desc, li * 128, 128, buf, q, lane);
    // Tail: widths 64,32,16,8,4,2,1.
    layer_step<4>(desc, 2048, 64, buf, q, lane);
    layer_step<2>(desc, 2112, 32, buf, q, lane);
    layer_step<1>(desc, 2144, 16, buf, q, lane);
    layer_step<1>(desc, 2160,  8, buf, q, lane);
    layer_step<1>(desc, 2168,  4, buf, q, lane);
    layer_step<1>(desc, 2172,  2, buf, q, lane);
    layer_step<1>(desc, 2174,  1, buf, q, lane);

    // Final layer width 1: row 0, 4 packed cells per lane.
    if (t < CELLS) {
        int cl = t & 63, h = t >> 6;
        uint2 p = buf[0][cl];                 // broadcast read
        unsigned int u = (h < 2) ? p.x : p.y;
        __half2 hh = *reinterpret_cast<__half2*>(&u);
        out[base + t] = (h & 1) ? __high2float(hh) : __low2float(hh);
    }
}

extern "C" void kernel_launch(void* const* d_in, const int* in_sizes, int n_in,
                              void* d_out, int out_size, void* d_ws, size_t ws_size,
                              hipStream_t stream) {
    const float* x  = (const float*)d_in[0];
    const float* W  = (const float*)d_in[1];
    const int*   ia = (const int*)d_in[2];
    const int*   ib = (const int*)d_in[3];
    NodeDesc* desc  = (NodeDesc*)d_ws;   // 2175 * 32 B = 69.6 KB scratch

    coeff_kernel<<<(TOTAL_NODES + 255) / 256, 256, 0, stream>>>(W, ia, ib, desc);

    const int grid = N_CELLS / CELLS;    // 1024 blocks
    net_kernel<<<grid, BLOCK, 0, stream>>>(x, desc, (float*)d_out);
}

// Round 8
// 167.480 us; speedup vs baseline: 1.1080x; 1.0456x over previous
//
#include <hip/hip_runtime.h>
#include <hip/hip_fp16.h>
#include <hip/hip_bf16.h>

// Logic-gate network: 23 layers, widths [128]*16 + [64,32,16,8,4,2,1].
// Node j: out = c0 + c1*a + c2*b + c3*a*b; c = softmax(W[j]) @ GATE_COEFFS.
// N_CELLS = 262144 independent cells.
//
// R8: R7 structure (1024 thr, 4 fp16 cells/lane, b64 DS path, 64KB LDS,
// 2 blocks/CU = 32 waves/CU) but __launch_bounds__(1024,4). R4/R7 lesson:
// the (...,8) bound made the compiler clamp to 32 VGPR and spill res[]
// (WRITE_SIZE 21.5MB scratch tax). PER=8 needs only ~40 VGPR <= 64, so a
// relaxed bound still yields 8 waves/SIMD occupancy WITHOUT the spill.
// fp16 storage / fp32 math (absmax 1.95e-3, thr 9.26e-3).

#define N_CELLS     262144
#define TOTAL_NODES 2175
#define CELLS       256        // cells per block (64 lanes x 4 packed fp16)
#define BLOCK       1024       // 16 waves
#define ROWS        128        // max layer width

__device__ const float GC[16][4] = {
    {0, 0, 0, 0}, {0, 0, 0, 1}, {0, 1, 0, -1}, {0, 1, 0, 0},
    {0, 0, 1, -1}, {0, 0, 1, 0}, {0, 1, 1, -2}, {0, 1, 1, -1},
    {1, -1, -1, 1}, {1, -1, -1, 2}, {1, 0, -1, 0}, {1, 0, -1, 1},
    {1, -1, 0, 0}, {1, -1, 0, 1}, {1, 0, 0, -1}, {1, 0, 0, 0}
};

// 32B node descriptor: one wave-uniform scalar-load stream in the hot loop.
struct __align__(32) NodeDesc {
    float c0, c1, c2, c3;
    int   ia, ib;
    int   pad0, pad1;
};

// ---- Kernel A: build per-node descriptors: c = softmax(W[node]) @ GC ----
__global__ void coeff_kernel(const float* __restrict__ W,
                             const int* __restrict__ idx_a,
                             const int* __restrict__ idx_b,
                             NodeDesc* __restrict__ dout) {
    int node = blockIdx.x * blockDim.x + threadIdx.x;
    if (node >= TOTAL_NODES) return;
    const float* w = W + node * 16;
    float v[16];
    float m = -1e30f;
    #pragma unroll
    for (int i = 0; i < 16; ++i) { v[i] = w[i]; m = fmaxf(m, v[i]); }
    float s = 0.f;
    #pragma unroll
    for (int i = 0; i < 16; ++i) { v[i] = expf(v[i] - m); s += v[i]; }
    float inv = 1.0f / s;
    float c0 = 0.f, c1 = 0.f, c2 = 0.f, c3 = 0.f;
    #pragma unroll
    for (int i = 0; i < 16; ++i) {
        float p = v[i] * inv;
        c0 += p * GC[i][0];
        c1 += p * GC[i][1];
        c2 += p * GC[i][2];
        c3 += p * GC[i][3];
    }
    NodeDesc d;
    d.c0 = c0; d.c1 = c1; d.c2 = c2; d.c3 = c3;
    d.ia = idx_a[node]; d.ib = idx_b[node];
    d.pad0 = 0; d.pad1 = 0;
    dout[node] = d;
}

__device__ __forceinline__ float2 h2f(unsigned int u) {
    __half2 h = *reinterpret_cast<__half2*>(&u);
    return __half22float2(h);
}
__device__ __forceinline__ unsigned int f2h(float lo, float hi) {
    __half2 h = __floats2half2_rn(lo, hi);
    return *reinterpret_cast<unsigned int*>(&h);
}

// One layer: wave q computes nodes [q*PER, q*PER+PER).
// Phase 1: gather + compute into res[] (regs). Barrier.
// Phase 2: write res[] over the (now dead) input rows. Barrier.
template<int PER>
__device__ __forceinline__ void layer_step(const NodeDesc* __restrict__ desc,
                                           int off, int w,
                                           uint2 (* __restrict__ buf)[64],
                                           int q, int lane) {
    const int n0 = q * PER;
    uint2 res[PER];
    const bool active = (n0 < w);

    if (active) {
        #pragma unroll
        for (int j = 0; j < PER; ++j) {
            int nu = __builtin_amdgcn_readfirstlane(n0 + j);
            NodeDesc d = desc[off + nu];          // scalar loads
            uint2 ap = buf[d.ia][lane];           // ds_read_b64
            uint2 bp = buf[d.ib][lane];
            float2 a01 = h2f(ap.x), a23 = h2f(ap.y);
            float2 b01 = h2f(bp.x), b23 = h2f(bp.y);
            // out = a*(c1 + c3*b) + (c0 + c2*b)   (3 FMA per cell, f32)
            float r0 = fmaf(a01.x, fmaf(d.c3, b01.x, d.c1), fmaf(d.c2, b01.x, d.c0));
            float r1 = fmaf(a01.y, fmaf(d.c3, b01.y, d.c1), fmaf(d.c2, b01.y, d.c0));
            float r2 = fmaf(a23.x, fmaf(d.c3, b23.x, d.c1), fmaf(d.c2, b23.x, d.c0));
            float r3 = fmaf(a23.y, fmaf(d.c3, b23.y, d.c1), fmaf(d.c2, b23.y, d.c0));
            res[j].x = f2h(r0, r1);
            res[j].y = f2h(r2, r3);
        }
    }
    __syncthreads();                              // all reads done
    if (active) {
        #pragma unroll
        for (int j = 0; j < PER; ++j) {
            int nu = __builtin_amdgcn_readfirstlane(n0 + j);
            buf[nu][lane] = res[j];               // ds_write_b64
        }
    }
    __syncthreads();                              // all writes done
}

// ---- Kernel B: the network. 256 cells/block; single 64KB LDS buffer. ----
__global__ __launch_bounds__(BLOCK, 4)
void net_kernel(const float* __restrict__ x,
                const NodeDesc* __restrict__ desc,
                float* __restrict__ out) {
    // 128 rows * 64 lanes * 8B = 64 KB -> 2 blocks/CU (32 waves/CU if VGPR<=64).
    __shared__ uint2 buf[ROWS][64];

    const int t    = threadIdx.x;
    const int lane = t & 63;        // cells lane, lane+64, lane+128, lane+192
    const int q    = t >> 6;        // wave id 0..15
    const size_t base = (size_t)blockIdx.x * CELLS;

    // Stage x (256 cells x 16 f32 = 16 KB) -> packed fp16 buf[k][lane][4].
    {
        const float4* xv = reinterpret_cast<const float4*>(x + base * 16);
        __half* hp = reinterpret_cast<__half*>(&buf[0][0]);
        float4 v = xv[t];                 // coalesced: 1024 float4 = 4096 f32
        int c  = t >> 2;                  // cell 0..255
        int k  = (t & 3) << 2;            // feature base
        int h  = c >> 6;                  // sub-slot 0..3
        int cl = c & 63;
        hp[((k + 0) * 64 + cl) * 4 + h] = __float2half(v.x);
        hp[((k + 1) * 64 + cl) * 4 + h] = __float2half(v.y);
        hp[((k + 2) * 64 + cl) * 4 + h] = __float2half(v.z);
        hp[((k + 3) * 64 + cl) * 4 + h] = __float2half(v.w);
    }
    __syncthreads();

    // Layers 0..15: width 128, PER=8 (16 waves).
    #pragma unroll 1
    for (int li = 0; li < 16; ++li)
        layer_step<8>(desc, li * 128, 128, buf, q, lane);
    // Tail: widths 64,32,16,8,4,2,1.
    layer_step<4>(desc, 2048, 64, buf, q, lane);
    layer_step<2>(desc, 2112, 32, buf, q, lane);
    layer_step<1>(desc, 2144, 16, buf, q, lane);
    layer_step<1>(desc, 2160,  8, buf, q, lane);
    layer_step<1>(desc, 2168,  4, buf, q, lane);
    layer_step<1>(desc, 2172,  2, buf, q, lane);
    layer_step<1>(desc, 2174,  1, buf, q, lane);

    // Final layer width 1: row 0, 4 packed cells per lane.
    if (t < CELLS) {
        int cl = t & 63, h = t >> 6;
        uint2 p = buf[0][cl];                 // broadcast read
        unsigned int u = (h < 2) ? p.x : p.y;
        __half2 hh = *reinterpret_cast<__half2*>(&u);
        out[base + t] = (h & 1) ? __high2float(hh) : __low2float(hh);
    }
}

extern "C" void kernel_launch(void* const* d_in, const int* in_sizes, int n_in,
                              void* d_out, int out_size, void* d_ws, size_t ws_size,
                              hipStream_t stream) {
    const float* x  = (const float*)d_in[0];
    const float* W  = (const float*)d_in[1];
    const int*   ia = (const int*)d_in[2];
    const int*   ib = (const int*)d_in[3];
    NodeDesc* desc  = (NodeDesc*)d_ws;   // 2175 * 32 B = 69.6 KB scratch

    coeff_kernel<<<(TOTAL_NODES + 255) / 256, 256, 0, stream>>>(W, ia, ib, desc);

    const int grid = N_CELLS / CELLS;    // 1024 blocks
    net_kernel<<<grid, BLOCK, 0, stream>>>(x, desc, (float*)d_out);
}

// Round 9
// 136.162 us; speedup vs baseline: 1.3628x; 1.2300x over previous
//
#include <hip/hip_runtime.h>
#include <hip/hip_fp16.h>
#include <hip/hip_bf16.h>

// Logic-gate network: 23 layers, widths [128]*16 + [64,32,16,8,4,2,1].
// Node j: out = c0 + c1*a + c2*b + c3*a*b; c = softmax(W[j]) @ GATE_COEFFS.
// N_CELLS = 262144 independent cells.
//
// R9: R8 structure (1024 thr, 4 fp16 cells/lane, b64 DS path, 64KB LDS,
// 2 blocks/CU = 32 waves/CU, no spill) + PACKED FP16 MATH. R8 counters:
// VALU 64% x 110us ~= 70us busy, mostly cvt f16<->f32 round-trip (8 cvt +
// 12 f32 fma + 4 pack per unit). v_pk_fma_f16 (__hfma2) computes
// a*(c1+c3*b)+(c0+c2*b) in 6 pk-FMAs per 4-cell unit -> VALU ~30us,
// exposing the DS pipe (~80us) as the wall. Coeffs pre-packed as dup'd
// half2 in the descriptor. Precision: adds 2 roundings/layer on top of the
// existing storage rounding; measured 1.95e-3 -> predict 4-6e-3 < 9.26e-3.

#define N_CELLS     262144
#define TOTAL_NODES 2175
#define CELLS       256        // cells per block (64 lanes x 4 packed fp16)
#define BLOCK       1024       // 16 waves
#define ROWS        128        // max layer width

__device__ const float GC[16][4] = {
    {0, 0, 0, 0}, {0, 0, 0, 1}, {0, 1, 0, -1}, {0, 1, 0, 0},
    {0, 0, 1, -1}, {0, 0, 1, 0}, {0, 1, 1, -2}, {0, 1, 1, -1},
    {1, -1, -1, 1}, {1, -1, -1, 2}, {1, 0, -1, 0}, {1, 0, -1, 1},
    {1, -1, 0, 0}, {1, -1, 0, 1}, {1, 0, 0, -1}, {1, 0, 0, 0}
};

// 32B node descriptor: coeffs as DUPLICATED half2 (ready for v_pk_fma_f16).
struct __align__(32) NodeDesc {
    unsigned int c0, c1, c2, c3;   // each = __half2 {c, c}
    int ia, ib;
    int pad0, pad1;
};

__device__ __forceinline__ unsigned int h2u(__half2 h) {
    return *reinterpret_cast<unsigned int*>(&h);
}
__device__ __forceinline__ __half2 u2h2(unsigned int u) {
    return *reinterpret_cast<__half2*>(&u);
}

// ---- Kernel A: build per-node descriptors: c = softmax(W[node]) @ GC ----
__global__ void coeff_kernel(const float* __restrict__ W,
                             const int* __restrict__ idx_a,
                             const int* __restrict__ idx_b,
                             NodeDesc* __restrict__ dout) {
    int node = blockIdx.x * blockDim.x + threadIdx.x;
    if (node >= TOTAL_NODES) return;
    const float* w = W + node * 16;
    float v[16];
    float m = -1e30f;
    #pragma unroll
    for (int i = 0; i < 16; ++i) { v[i] = w[i]; m = fmaxf(m, v[i]); }
    float s = 0.f;
    #pragma unroll
    for (int i = 0; i < 16; ++i) { v[i] = expf(v[i] - m); s += v[i]; }
    float inv = 1.0f / s;
    float c0 = 0.f, c1 = 0.f, c2 = 0.f, c3 = 0.f;
    #pragma unroll
    for (int i = 0; i < 16; ++i) {
        float p = v[i] * inv;
        c0 += p * GC[i][0];
        c1 += p * GC[i][1];
        c2 += p * GC[i][2];
        c3 += p * GC[i][3];
    }
    NodeDesc d;
    d.c0 = h2u(__half2half2(__float2half(c0)));
    d.c1 = h2u(__half2half2(__float2half(c1)));
    d.c2 = h2u(__half2half2(__float2half(c2)));
    d.c3 = h2u(__half2half2(__float2half(c3)));
    d.ia = idx_a[node]; d.ib = idx_b[node];
    d.pad0 = 0; d.pad1 = 0;
    dout[node] = d;
}

// One layer: wave q computes nodes [q*PER, q*PER+PER).
// Phase 1: gather + compute into res[] (regs, pure pk-fp16). Barrier.
// Phase 2: write res[] over the (now dead) input rows. Barrier.
template<int PER>
__device__ __forceinline__ void layer_step(const NodeDesc* __restrict__ desc,
                                           int off, int w,
                                           uint2 (* __restrict__ buf)[64],
                                           int q, int lane) {
    const int n0 = q * PER;
    uint2 res[PER];
    const bool active = (n0 < w);

    if (active) {
        #pragma unroll
        for (int j = 0; j < PER; ++j) {
            int nu = __builtin_amdgcn_readfirstlane(n0 + j);
            NodeDesc d = desc[off + nu];          // scalar loads
            __half2 c0 = u2h2(d.c0), c1 = u2h2(d.c1);
            __half2 c2 = u2h2(d.c2), c3 = u2h2(d.c3);
            uint2 ap = buf[d.ia][lane];           // ds_read_b64
            uint2 bp = buf[d.ib][lane];
            __half2 a0 = u2h2(ap.x), a1 = u2h2(ap.y);
            __half2 b0 = u2h2(bp.x), b1 = u2h2(bp.y);
            // out = a*(c1 + c3*b) + (c0 + c2*b)   (3 v_pk_fma_f16 per half2)
            __half2 r0 = __hfma2(a0, __hfma2(c3, b0, c1), __hfma2(c2, b0, c0));
            __half2 r1 = __hfma2(a1, __hfma2(c3, b1, c1), __hfma2(c2, b1, c0));
            res[j].x = h2u(r0);
            res[j].y = h2u(r1);
        }
    }
    __syncthreads();                              // all reads done
    if (active) {
        #pragma unroll
        for (int j = 0; j < PER; ++j) {
            int nu = __builtin_amdgcn_readfirstlane(n0 + j);
            buf[nu][lane] = res[j];               // ds_write_b64
        }
    }
    __syncthreads();                              // all writes done
}

// ---- Kernel B: the network. 256 cells/block; single 64KB LDS buffer. ----
__global__ __launch_bounds__(BLOCK, 4)
void net_kernel(const float* __restrict__ x,
                const NodeDesc* __restrict__ desc,
                float* __restrict__ out) {
    // 128 rows * 64 lanes * 8B = 64 KB -> 2 blocks/CU (32 waves/CU).
    __shared__ uint2 buf[ROWS][64];

    const int t    = threadIdx.x;
    const int lane = t & 63;        // cells lane, lane+64, lane+128, lane+192
    const int q    = t >> 6;        // wave id 0..15
    const size_t base = (size_t)blockIdx.x * CELLS;

    // Stage x (256 cells x 16 f32 = 16 KB) -> packed fp16 buf[k][lane][4].
    {
        const float4* xv = reinterpret_cast<const float4*>(x + base * 16);
        __half* hp = reinterpret_cast<__half*>(&buf[0][0]);
        float4 v = xv[t];                 // coalesced: 1024 float4 = 4096 f32
        int c  = t >> 2;                  // cell 0..255
        int k  = (t & 3) << 2;            // feature base
        int h  = c >> 6;                  // sub-slot 0..3
        int cl = c & 63;
        hp[((k + 0) * 64 + cl) * 4 + h] = __float2half(v.x);
        hp[((k + 1) * 64 + cl) * 4 + h] = __float2half(v.y);
        hp[((k + 2) * 64 + cl) * 4 + h] = __float2half(v.z);
        hp[((k + 3) * 64 + cl) * 4 + h] = __float2half(v.w);
    }
    __syncthreads();

    // Layers 0..15: width 128, PER=8 (16 waves).
    #pragma unroll 1
    for (int li = 0; li < 16; ++li)
        layer_step<8>(desc, li * 128, 128, buf, q, lane);
    // Tail: widths 64,32,16,8,4,2,1.
    layer_step<4>(desc, 2048, 64, buf, q, lane);
    layer_step<2>(desc, 2112, 32, buf, q, lane);
    layer_step<1>(desc, 2144, 16, buf, q, lane);
    layer_step<1>(desc, 2160,  8, buf, q, lane);
    layer_step<1>(desc, 2168,  4, buf, q, lane);
    layer_step<1>(desc, 2172,  2, buf, q, lane);
    layer_step<1>(desc, 2174,  1, buf, q, lane);

    // Final layer width 1: row 0, 4 packed cells per lane.
    if (t < CELLS) {
        int cl = t & 63, h = t >> 6;
        uint2 p = buf[0][cl];                 // broadcast read
        unsigned int u = (h < 2) ? p.x : p.y;
        __half2 hh = u2h2(u);
        out[base + t] = (h & 1) ? __high2float(hh) : __low2float(hh);
    }
}

extern "C" void kernel_launch(void* const* d_in, const int* in_sizes, int n_in,
                              void* d_out, int out_size, void* d_ws, size_t ws_size,
                              hipStream_t stream) {
    const float* x  = (const float*)d_in[0];
    const float* W  = (const float*)d_in[1];
    const int*   ia = (const int*)d_in[2];
    const int*   ib = (const int*)d_in[3];
    NodeDesc* desc  = (NodeDesc*)d_ws;   // 2175 * 32 B = 69.6 KB scratch

    coeff_kernel<<<(TOTAL_NODES + 255) / 256, 256, 0, stream>>>(W, ia, ib, desc);

    const int grid = N_CELLS / CELLS;    // 1024 blocks
    net_kernel<<<grid, BLOCK, 0, stream>>>(x, desc, (float*)d_out);
}